// Round 5
// baseline (1853.755 us; speedup 1.0000x reference)
//
#include <hip/hip_runtime.h>
#include <cmath>

#define NLV 16
#define LOG2_HASH 19
#define HSZ (1u << LOG2_HASH)
#define HMASK (HSZ - 1u)
#define HP1 2654435761u
#define HP2 805459861u

typedef float f2v __attribute__((ext_vector_type(2)));
typedef float f4v __attribute__((ext_vector_type(4)));

struct HEParams {
    int   res[NLV];
    float resf[NLV];
};

// ---------------- dense levels 0..4 (tables total ~2.5MB, L2-resident) ------
template<bool STAGED>
__global__ __launch_bounds__(256) void he_dense(
    const float* __restrict__ pos, const float* __restrict__ emb,
    float* __restrict__ dst,   // STAGED: ws base [16][n][2]; else out [n][32]
    int n, HEParams prm)
{
    __shared__ float spos[256 * 3];
    const int tid = threadIdx.x;
    const int bbase = blockIdx.x * 256;
    #pragma unroll
    for (int i = 0; i < 3; ++i) {
        const int g = bbase * 3 + tid + i * 256;
        if (g < n * 3) spos[tid + i * 256] = __builtin_nontemporal_load(pos + g);
    }
    __syncthreads();
    const int p = bbase + tid;
    if (p >= n) return;
    const float x = spos[tid * 3 + 0];
    const float y = spos[tid * 3 + 1];
    const float z = spos[tid * 3 + 2];

    #pragma unroll
    for (int l = 0; l < 5; ++l) {
        const float rf = prm.resf[l];
        const float sx = x * rf, sy = y * rf, sz = z * rf;
        const float fx = floorf(sx), fy = floorf(sy), fz = floorf(sz);
        const float wx = sx - fx, wy = sy - fy, wz = sz - fz;
        const int r1 = prm.res[l] + 1, r1s = r1 * r1;
        const int base = (int)fx * r1s + (int)fy * r1 + (int)fz;

        const f2v* __restrict__ tab = (const f2v*)(emb + (size_t)l * HSZ * 2);
        const f2v f000 = tab[base];
        const f2v f001 = tab[base + 1];
        const f2v f010 = tab[base + r1];
        const f2v f011 = tab[base + r1 + 1];
        const f2v f100 = tab[base + r1s];
        const f2v f101 = tab[base + r1s + 1];
        const f2v f110 = tab[base + r1s + r1];
        const f2v f111 = tab[base + r1s + r1 + 1];

        const float omx = 1.f - wx, omy = 1.f - wy, omz = 1.f - wz;
        const f2v c00 = f000 * omx + f100 * wx;
        const f2v c01 = f001 * omx + f101 * wx;
        const f2v c10 = f010 * omx + f110 * wx;
        const f2v c11 = f011 * omx + f111 * wx;
        const f2v c0 = c00 * omy + c10 * wy;
        const f2v c1 = c01 * omy + c11 * wy;
        const f2v r  = c0 * omz + c1 * wz;

        if (STAGED) {
            __builtin_nontemporal_store(r, (f2v*)dst + (size_t)l * n + p);
        } else {
            *(f2v*)(dst + (size_t)p * 32 + 2 * l) = r;
        }
    }
}

// ---------------- one hashed level (table 4MB, L2-resident per pass) --------
template<bool STAGED>
__global__ __launch_bounds__(256) void he_hash(
    const float* __restrict__ pos,
    const float* __restrict__ tab_,  // emb + l*HSZ*2
    float* __restrict__ dstl,        // STAGED: ws + l*n*2 ([n] f2v); else out + 2l
    int n, float rf)
{
    __shared__ float spos[256 * 3];
    const int tid = threadIdx.x;
    const int bbase = blockIdx.x * 256;
    #pragma unroll
    for (int i = 0; i < 3; ++i) {
        const int g = bbase * 3 + tid + i * 256;
        if (g < n * 3) spos[tid + i * 256] = __builtin_nontemporal_load(pos + g);
    }
    __syncthreads();
    const int p = bbase + tid;
    if (p >= n) return;
    const float x = spos[tid * 3 + 0];
    const float y = spos[tid * 3 + 1];
    const float z = spos[tid * 3 + 2];

    const float sx = x * rf, sy = y * rf, sz = z * rf;
    const float fx = floorf(sx), fy = floorf(sy), fz = floorf(sz);
    const float wx = sx - fx, wy = sy - fy, wz = sz - fz;

    const unsigned hx0 = (unsigned)(int)fx,        hx1 = hx0 + 1u;
    const unsigned hy0 = (unsigned)(int)fy * HP1,  hy1 = hy0 + HP1;
    const unsigned hz0 = (unsigned)(int)fz * HP2,  hz1 = hz0 + HP2;
    const unsigned t00 = hy0 ^ hz0, t01 = hy0 ^ hz1;
    const unsigned t10 = hy1 ^ hz0, t11 = hy1 ^ hz1;

    const f2v* __restrict__ tab = (const f2v*)tab_;
    const f2v f000 = tab[(hx0 ^ t00) & HMASK];
    const f2v f001 = tab[(hx0 ^ t01) & HMASK];
    const f2v f010 = tab[(hx0 ^ t10) & HMASK];
    const f2v f011 = tab[(hx0 ^ t11) & HMASK];
    const f2v f100 = tab[(hx1 ^ t00) & HMASK];
    const f2v f101 = tab[(hx1 ^ t01) & HMASK];
    const f2v f110 = tab[(hx1 ^ t10) & HMASK];
    const f2v f111 = tab[(hx1 ^ t11) & HMASK];

    const float omx = 1.f - wx, omy = 1.f - wy, omz = 1.f - wz;
    const f2v c00 = f000 * omx + f100 * wx;
    const f2v c01 = f001 * omx + f101 * wx;
    const f2v c10 = f010 * omx + f110 * wx;
    const f2v c11 = f011 * omx + f111 * wx;
    const f2v c0 = c00 * omy + c10 * wy;
    const f2v c1 = c01 * omy + c11 * wy;
    const f2v r  = c0 * omz + c1 * wz;

    if (STAGED) {
        __builtin_nontemporal_store(r, (f2v*)dstl + p);
    } else {
        *(f2v*)(dstl + (size_t)p * 32) = r;
    }
}

// ---------------- transpose ws[16][n][2] -> out[n][32] ----------------------
__global__ __launch_bounds__(256) void he_tr(
    const float* __restrict__ ws, float* __restrict__ out, int n)
{
    const int p = blockIdx.x * 256 + threadIdx.x;
    if (p >= n) return;
    f2v v[NLV];
    #pragma unroll
    for (int l = 0; l < NLV; ++l)
        v[l] = __builtin_nontemporal_load((const f2v*)ws + (size_t)l * n + p);
    f4v* __restrict__ o4 = (f4v*)(out + (size_t)p * 32);
    #pragma unroll
    for (int i = 0; i < 8; ++i) {
        f4v o; o.x = v[2*i].x; o.y = v[2*i].y; o.z = v[2*i+1].x; o.w = v[2*i+1].y;
        __builtin_nontemporal_store(o, o4 + i);
    }
}

extern "C" void kernel_launch(void* const* d_in, const int* in_sizes, int n_in,
                              void* d_out, int out_size, void* d_ws, size_t ws_size,
                              hipStream_t stream) {
    const float* pos = (const float*)d_in[0];
    const float* emb = (const float*)d_in[1];
    float*       out = (float*)d_out;
    float*       ws  = (float*)d_ws;
    const int n = in_sizes[0] / 3;

    HEParams prm;
    const double scale = std::exp((std::log(2048.0) - std::log(16.0)) / 15.0);
    for (int l = 0; l < NLV; ++l) {
        const int r = (int)std::floor(16.0 * std::pow(scale, (double)l));
        prm.res[l]  = r;
        prm.resf[l] = (float)r;
    }

    const int nb = (n + 255) / 256;
    const bool staged = ws_size >= (size_t)NLV * n * 2 * sizeof(float);

    if (staged) {
        hipLaunchKernelGGL(he_dense<true>, dim3(nb), dim3(256), 0, stream,
                           pos, emb, ws, n, prm);
        for (int l = 5; l < NLV; ++l)
            hipLaunchKernelGGL(he_hash<true>, dim3(nb), dim3(256), 0, stream,
                               pos, emb + (size_t)l * HSZ * 2,
                               ws + (size_t)l * n * 2, n, prm.resf[l]);
        hipLaunchKernelGGL(he_tr, dim3(nb), dim3(256), 0, stream, ws, out, n);
    } else {
        hipLaunchKernelGGL(he_dense<false>, dim3(nb), dim3(256), 0, stream,
                           pos, emb, out, n, prm);
        for (int l = 5; l < NLV; ++l)
            hipLaunchKernelGGL(he_hash<false>, dim3(nb), dim3(256), 0, stream,
                               pos, emb + (size_t)l * HSZ * 2,
                               out + 2 * l, n, prm.resf[l]);
    }
}